// Round 14
// baseline (463.784 us; speedup 1.0000x reference)
//
#include <hip/hip_runtime.h>

#define DEVINL __device__ __forceinline__

typedef unsigned short u16;
typedef __attribute__((ext_vector_type(8))) __bf16 bf16x8;
typedef __attribute__((ext_vector_type(4))) float f32x4;
typedef __attribute__((ext_vector_type(16))) float f32x16;

struct alignas(8) u16x4 { u16 x, y, z, w; };

#define MFMA16(a, b, c) __builtin_amdgcn_mfma_f32_16x16x32_bf16(a, b, c, 0, 0, 0)
#define MFMA32(a, b, c) __builtin_amdgcn_mfma_f32_32x32x16_bf16(a, b, c, 0, 0, 0)

// fp32 -> bf16 round-to-nearest-even
DEVINL u16 f2bf(float f) {
  unsigned u = __builtin_bit_cast(unsigned, f);
  u += 0x7fffu + ((u >> 16) & 1u);
  return (u16)(u >> 16);
}

DEVINL unsigned cvtpk_bf16(float lo, float hi) {
  unsigned r;
  asm("v_cvt_pk_bf16_f32 %0, %1, %2" : "=v"(r) : "v"(lo), "v"(hi));
  return r;
}

DEVINL void plane_swap(unsigned& a, unsigned& b) {
  asm("v_permlane32_swap_b32 %0, %1" : "+v"(a), "+v"(b));
}

DEVINL void gload_lds16(const u16* g, u16* l) {
  __builtin_amdgcn_global_load_lds((const __attribute__((address_space(1))) void*)g,
                                   (__attribute__((address_space(3))) void*)l,
                                   16, 0, 0);
}

// ---- swizzled LDS helpers, 16B chunks: LDS[r][c] = G[r][c ^ (r&7)] ----
DEVINL bf16x8 frag64(const u16* lds, int row, int cg) {
  int c = cg ^ (row & 7);
  return *(const bf16x8*)(lds + row * 64 + c * 8);
}
DEVINL bf16x8 frag128(const u16* lds, int row, int cg) {
  int c = cg ^ (row & 7);
  return *(const bf16x8*)(lds + row * 128 + c * 8);
}

// 512-thread staging (attn, 8 waves): 64x128 K tile, 2 loads/thread
DEVINL void stage_k512(const u16* g, u16* lds, int wave, int lane) {
#pragma unroll
  for (int t = 0; t < 2; ++t) {
    int r = t * 32 + wave * 4 + (lane >> 4);
    int cg = (lane & 15) ^ (r & 7);
    gload_lds16(g + (size_t)r * 128 + cg * 8, lds + (t * 32 + wave * 4) * 128);
  }
}
// 512-thread staging (attn, 8 waves): 128x64 V tile (ldg = global row stride)
DEVINL void stage_v512(const u16* g, int ldg, u16* lds, int wave, int lane) {
#pragma unroll
  for (int t = 0; t < 2; ++t) {
    int r = t * 64 + wave * 8 + (lane >> 3);
    int cg = (lane & 7) ^ (r & 7);
    gload_lds16(g + (size_t)r * ldg + cg * 8, lds + (t * 64 + wave * 8) * 64);
  }
}

// ---- 256x32 sub-tile machinery (64B rows, 4 chunks) for the ring-4 GEMM ----
DEVINL int perm32(int row) { return (row & 3) ^ ((row >> 2) & 3); }

DEVINL void stage32(const u16* g, int ldg, u16* lds, int q, int wave, int lane) {
  int row = q * 128 + wave * 16 + (lane >> 2);
  int cg = (lane & 3) ^ perm32(row);
  gload_lds16(g + (size_t)row * ldg + cg * 8, lds + (q * 128 + wave * 16) * 32);
}

DEVINL bf16x8 frag32(const u16* lds, int row, int lc) {
  int c = lc ^ perm32(row);
  return *(const bf16x8*)(lds + row * 32 + c * 8);
}

// ---------------- fused fp32 -> bf16 cast (all three inputs, one launch) ----------------
// blocks [0,1024): x (4M float4); [1024,1792): w_attn (3M); [1792,2048): w_proj (1M).
__global__ void __launch_bounds__(256) k_cast3(const float4* __restrict__ x,
                                               const float4* __restrict__ wa,
                                               const float4* __restrict__ wp,
                                               u16x4* __restrict__ xb,
                                               u16x4* __restrict__ wab,
                                               u16x4* __restrict__ wpb) {
  const int b = blockIdx.x;
  const float4* src;
  u16x4* dst;
  int n, i, stride;
  if (b < 1024) {
    src = x; dst = xb; n = 4194304;
    i = b * 256 + threadIdx.x; stride = 1024 * 256;
  } else if (b < 1792) {
    src = wa; dst = wab; n = 3145728;
    i = (b - 1024) * 256 + threadIdx.x; stride = 768 * 256;
  } else {
    src = wp; dst = wpb; n = 1048576;
    i = (b - 1792) * 256 + threadIdx.x; stride = 256 * 256;
  }
  for (; i < n; i += stride) {
    float4 f = src[i];
    u16x4 u;
    u.x = f2bf(f.x); u.y = f2bf(f.y); u.z = f2bf(f.z); u.w = f2bf(f.w);
    dst[i] = u;
  }
}

// ---------------- 256x256 ring-4 GEMM, m201-style paced phases ----------------
// A row-major (M,K), B row-major (N,K). 8 waves = 2(M) x 4(N); wave (wm,wn)
// owns C rows [wm*128,+128) x cols [wn*64,+64): acc[mf 0..7][nf 0..3].
// Ring: BK=32 sub-tiles in 4 LDS slots/operand (128KB). Step s, 2 phases,
// each phase = {ds_read this phase's frags ; stage 2 loads of tile s+3 ;
// s_barrier ; setprio(1) ; 16 MFMA ; setprio(0)} -- reads issue BEFORE the
// barrier, consume AFTER: the other waves' MFMA covers the ds_read latency
// (barrier-paced interleave, m201 mechanism; R11's preload variant let
// waves bunch on the LDS pipe -> 46% MfmaUtil).
// End of step: vmcnt(8) certifies tile s+1 (12 outstanding - its 4; tail
// 4/0), then barrier. Hazards: stage targets slot (s-1)&3, whose last
// readers (phase B of step s-1) precede that step's trailing barrier.
DEVINL void gemm_loop256(const u16* Ag, const u16* Bg, int K, u16* smem,
                         f32x4 acc[8][4], int wave, int lane) {
  const int wm = wave >> 2, wn = wave & 3;
  const int lr = lane & 15, lc = lane >> 4;

  // prologue: stage tiles 0,1,2 (12 loads/thread); certify tile 0
#pragma unroll
  for (int t = 0; t < 3; ++t) {
    u16* At = smem + t * 8192;
    u16* Bt = smem + 32768 + t * 8192;
    stage32(Ag + t * 32, K, At, 0, wave, lane);
    stage32(Ag + t * 32, K, At, 1, wave, lane);
    stage32(Bg + t * 32, K, Bt, 0, wave, lane);
    stage32(Bg + t * 32, K, Bt, 1, wave, lane);
  }
  asm volatile("s_waitcnt vmcnt(8)" ::: "memory");
  asm volatile("s_barrier" ::: "memory");

  const int nsteps = K / 32;
  for (int s = 0; s < nsteps; ++s) {
    const int slot = s & 3;
    const u16* Ac = smem + slot * 8192;
    const u16* Bc = smem + 32768 + slot * 8192;
    const bool do_stage = (s + 3 < nsteps);
    u16* An = smem + ((s + 3) & 3) * 8192;
    u16* Bn = smem + 32768 + ((s + 3) & 3) * 8192;
    const u16* Agn = Ag + (size_t)(s + 3) * 32;
    const u16* Bgn = Bg + (size_t)(s + 3) * 32;

    // ---- phase A: read bfr+aA(8), stage A(s+3), barrier, 16 MFMA ----
    bf16x8 bfr[4], aA[4];
#pragma unroll
    for (int nf = 0; nf < 4; ++nf)
      bfr[nf] = frag32(Bc, nf * 64 + wn * 16 + lr, lc);
#pragma unroll
    for (int mf = 0; mf < 4; ++mf)
      aA[mf] = frag32(Ac, wm * 128 + mf * 16 + lr, lc);
    if (do_stage) {
      stage32(Agn, K, An, 0, wave, lane);
      stage32(Agn, K, An, 1, wave, lane);
    }
    asm volatile("s_barrier" ::: "memory");
    __builtin_amdgcn_s_setprio(1);
#pragma unroll
    for (int mf = 0; mf < 4; ++mf)
#pragma unroll
      for (int nf = 0; nf < 4; ++nf)
        acc[mf][nf] = MFMA16(aA[mf], bfr[nf], acc[mf][nf]);
    __builtin_amdgcn_s_setprio(0);

    // ---- phase B: read aB(4), stage B(s+3), barrier, 16 MFMA ----
    bf16x8 aB[4];
#pragma unroll
    for (int mf = 0; mf < 4; ++mf)
      aB[mf] = frag32(Ac, wm * 128 + (mf + 4) * 16 + lr, lc);
    if (do_stage) {
      stage32(Bgn, K, Bn, 0, wave, lane);
      stage32(Bgn, K, Bn, 1, wave, lane);
    }
    asm volatile("s_barrier" ::: "memory");
    __builtin_amdgcn_s_setprio(1);
#pragma unroll
    for (int mf = 0; mf < 4; ++mf)
#pragma unroll
      for (int nf = 0; nf < 4; ++nf)
        acc[mf + 4][nf] = MFMA16(aB[mf], bfr[nf], acc[mf + 4][nf]);
    __builtin_amdgcn_s_setprio(0);

    // ---- end of step: certify tile s+1 (counted), barrier ----
    if (s + 3 < nsteps) {
      asm volatile("s_waitcnt vmcnt(8)" ::: "memory");
    } else if (s + 2 < nsteps) {
      asm volatile("s_waitcnt vmcnt(4)" ::: "memory");
    } else if (s + 1 < nsteps) {
      asm volatile("s_waitcnt vmcnt(0)" ::: "memory");
    }
    if (s + 1 < nsteps)
      asm volatile("s_barrier" ::: "memory");
  }
}

// ---------------- GEMM1: qkv = x @ w_attn^T, fused RoPE + scatter ----------------
// 2D-chunked XCD swizzle: XCD x owns tm in [8(x&3),+8) x tn in [12(x>>2),+12).
// tn 0-7: q, 8-15: k, 16-23: v; 256-col tile = 2 heads.
// q pre-scaled by (1/sqrt(D))*log2(e) so attention softmax runs in exp2 domain.
__global__ void __launch_bounds__(512, 2) k_gemm_qkv(const u16* __restrict__ xb,
                                                     const u16* __restrict__ wab,
                                                     u16* __restrict__ qb,
                                                     u16* __restrict__ kb,
                                                     u16* __restrict__ vtb) {
  extern __shared__ u16 smem[];
  int bid = blockIdx.x;
  const int xcd = bid & 7, local = bid >> 3;       // 96 blocks per XCD
  const int tm = (xcd & 3) * 8 + (local & 7);      // 32 tm
  const int tn = (xcd >> 2) * 12 + (local >> 3);   // 24 tn
  const int wave = threadIdx.x >> 6, lane = threadIdx.x & 63;
  const int wm = wave >> 2, wn = wave & 3;
  const int lr = lane & 15, lc = lane >> 4;

  f32x4 acc[8][4];
#pragma unroll
  for (int i = 0; i < 8; ++i)
#pragma unroll
    for (int n = 0; n < 4; ++n) acc[i][n] = f32x4{0.f, 0.f, 0.f, 0.f};

  gemm_loop256(xb + (size_t)tm * 256 * 2048, wab + (size_t)tn * 256 * 2048, 2048,
               smem, acc, wave, lane);

  const int sel = tn >> 3;
  const int hh = (tn & 7) * 2;
  const int m0 = tm * 256 + wm * 128;
  const int b = (tm * 256) >> 11;

  if (sel < 2) {
    u16* dst = sel ? kb : qb;
    // q: fold 1/sqrt(128) * log2(e) (exp2-domain softmax)
    const float qs = sel ? 1.0f : 0.12751745f;
    const int d = wn * 16 + lr;  // d in [0,64)
    const float invf = __expf(-0.14391156631f * (float)d);
#pragma unroll
    for (int mf = 0; mf < 8; ++mf) {
#pragma unroll
      for (int j = 0; j < 4; ++j) {
        int t = (m0 + mf * 16 + lc * 4 + j) & 2047;
        float ang = (float)t * invf;
        float s, c;
        __sincosf(ang, &s, &c);
#pragma unroll
        for (int hp = 0; hp < 2; ++hp) {
          float lo = acc[mf][2 * hp][j];
          float hi = acc[mf][2 * hp + 1][j];
          size_t rowp = ((size_t)(b * 16 + hh + hp) * 2048 + t) * 128;
          dst[rowp + d] = f2bf((lo * c - hi * s) * qs);
          dst[rowp + d + 64] = f2bf((hi * c + lo * s) * qs);
        }
      }
    }
  } else {
    // v -> (B,H,D,T) transposed; pack 4 consecutive t (j dim) per store
#pragma unroll
    for (int mf = 0; mf < 8; ++mf) {
      int t0 = (m0 + mf * 16 + lc * 4) & 2047;
#pragma unroll
      for (int nf = 0; nf < 4; ++nf) {
        int d = wn * 16 + lr + (nf & 1) * 64;
        int h = hh + (nf >> 1);
        u16x4 pk;
        pk.x = f2bf(acc[mf][nf][0]);
        pk.y = f2bf(acc[mf][nf][1]);
        pk.z = f2bf(acc[mf][nf][2]);
        pk.w = f2bf(acc[mf][nf][3]);
        *(u16x4*)(vtb + ((size_t)(b * 16 + h) * 128 + d) * 2048 + t0) = pk;
      }
    }
  }
}

// ---------------- GEMM2: out = y @ w_proj^T (fp32 out) ----------------
__global__ void __launch_bounds__(512, 2) k_gemm_proj(const u16* __restrict__ yb,
                                                      const u16* __restrict__ wpb,
                                                      float* __restrict__ out) {
  extern __shared__ u16 smem[];
  int bid = blockIdx.x;
  int sw = (bid & 7) * 32 + (bid >> 3);  // 256 = 8 * 32, bijective
  const int tm = sw >> 3, tn = sw & 7;   // XCD x -> tm in [4x, 4x+3]
  const int wave = threadIdx.x >> 6, lane = threadIdx.x & 63;
  const int wm = wave >> 2, wn = wave & 3;
  const int lr = lane & 15, lc = lane >> 4;

  f32x4 acc[8][4];
#pragma unroll
  for (int i = 0; i < 8; ++i)
#pragma unroll
    for (int n = 0; n < 4; ++n) acc[i][n] = f32x4{0.f, 0.f, 0.f, 0.f};

  gemm_loop256(yb + (size_t)tm * 256 * 2048, wpb + (size_t)tn * 256 * 2048, 2048,
               smem, acc, wave, lane);

  const int m0 = tm * 256 + wm * 128;
#pragma unroll
  for (int mf = 0; mf < 8; ++mf) {
#pragma unroll
    for (int j = 0; j < 4; ++j) {
      int gr = m0 + mf * 16 + lc * 4 + j;
      float* op = out + (size_t)gr * 2048 + tn * 256 + wn * 16 + lr;
#pragma unroll
      for (int nf = 0; nf < 4; ++nf) op[nf * 64] = acc[mf][nf][j];
    }
  }
}

// ---------------- flash attention, 8-wave blocks (unchanged from R9/R10) ----------------
__global__ void __launch_bounds__(512) k_attn(const u16* __restrict__ qg,
                                              const u16* __restrict__ kg,
                                              const u16* __restrict__ vtg,
                                              u16* __restrict__ yg) {
  __shared__ u16 Ks[2][64 * 128];  // [buf][kv][d], 32 KB
  __shared__ u16 Vs[2][128 * 64];  // [buf][d][kv], 32 KB
  int bid = blockIdx.x;
  int sw = (bid & 7) * 64 + (bid >> 3);  // 512 = 8 * 64, bijective
  const int qt = sw & 7, bh = sw >> 3;   // XCD x -> 8 heads, all their q-tiles
  const int wave = threadIdx.x >> 6, lane = threadIdx.x & 63;
  const int hi = lane >> 5, ln = lane & 31;

  const u16* qbh = qg + (size_t)bh * (2048 * 128);
  const u16* kbh = kg + (size_t)bh * (2048 * 128);
  const u16* vbh = vtg + (size_t)bh * (128 * 2048);
  const int qrow0 = qt * 256 + wave * 32;

  // hoist Q (B-operand): lane holds Q[q=ln][d = kc*16 + hi*8 .. +7]
  bf16x8 qf[8];
#pragma unroll
  for (int kc = 0; kc < 8; ++kc)
    qf[kc] = *(const bf16x8*)(qbh + (size_t)(qrow0 + ln) * 128 + kc * 16 + hi * 8);

  f32x16 yacc[4];
#pragma unroll
  for (int nd = 0; nd < 4; ++nd)
#pragma unroll
    for (int r = 0; r < 16; ++r) yacc[nd][r] = 0.f;
  float m = -1e30f, l = 0.f;

  stage_k512(kbh, Ks[0], wave, lane);
  stage_v512(vbh, 2048, Vs[0], wave, lane);
  __syncthreads();

  int buf = 0;
  for (int kv0 = 0; kv0 < 2048; kv0 += 64) {
    if (kv0 + 64 < 2048) {
      stage_k512(kbh + (size_t)(kv0 + 64) * 128, Ks[buf ^ 1], wave, lane);
      stage_v512(vbh + kv0 + 64, 2048, Vs[buf ^ 1], wave, lane);
    }
    const u16* Kb = Ks[buf];
    const u16* Vb = Vs[buf];

    // QK^T: st[h2] = S^T[kv = h2*32 .. +32][q]
    f32x16 st[2];
#pragma unroll
    for (int h2 = 0; h2 < 2; ++h2)
#pragma unroll
      for (int r = 0; r < 16; ++r) st[h2][r] = 0.f;
    __builtin_amdgcn_s_setprio(1);
#pragma unroll
    for (int kc = 0; kc < 8; ++kc) {
      bf16x8 a0 = frag128(Kb, ln, kc * 2 + hi);
      bf16x8 a1 = frag128(Kb, 32 + ln, kc * 2 + hi);
      st[0] = MFMA32(a0, qf[kc], st[0]);
      st[1] = MFMA32(a1, qf[kc], st[1]);
    }
    __builtin_amdgcn_s_setprio(0);

    float t8[8];
#pragma unroll
    for (int i = 0; i < 8; ++i)
      t8[i] = fmaxf(fmaxf(st[0][i], st[0][i + 8]), fmaxf(st[1][i], st[1][i + 8]));
    float pmax = fmaxf(fmaxf(fmaxf(t8[0], t8[4]), fmaxf(t8[1], t8[5])),
                       fmaxf(fmaxf(t8[2], t8[6]), fmaxf(t8[3], t8[7])));
    pmax = fmaxf(pmax, __shfl_xor(pmax, 32));

    // defer-max: THR = 8 * log2(e) in exp2 domain
    if (__any(pmax - m > 11.5415603f)) {
      float mn = fmaxf(m, pmax);
      float al = __builtin_amdgcn_exp2f(m - mn);
      m = mn;
      l *= al;
#pragma unroll
      for (int nd = 0; nd < 4; ++nd)
#pragma unroll
        for (int r = 0; r < 16; ++r) yacc[nd][r] *= al;
    }

    float sa0 = 0.f, sa1 = 0.f, sa2 = 0.f, sa3 = 0.f;
#pragma unroll
    for (int h2 = 0; h2 < 2; ++h2) {
#pragma unroll
      for (int r = 0; r < 16; ++r) {
        float e = __builtin_amdgcn_exp2f(st[h2][r] - m);
        st[h2][r] = e;
        if ((r & 3) == 0) sa0 += e;
        else if ((r & 3) == 1) sa1 += e;
        else if ((r & 3) == 2) sa2 += e;
        else sa3 += e;
      }
    }
    float ssum = (sa0 + sa1) + (sa2 + sa3);
    ssum += __shfl_xor(ssum, 32);
    l += ssum;

    unsigned wa[2][4], wb[2][4];
#pragma unroll
    for (int h2 = 0; h2 < 2; ++h2)
#pragma unroll
      for (int q8 = 0; q8 < 4; ++q8) {
        wa[h2][q8] = cvtpk_bf16(st[h2][q8 * 4 + 0], st[h2][q8 * 4 + 1]);
        wb[h2][q8] = cvtpk_bf16(st[h2][q8 * 4 + 2], st[h2][q8 * 4 + 3]);
      }

    // PV: 4 kv16-blocks; pa assembled by permlane32_swap (both outputs used)
    __builtin_amdgcn_s_setprio(1);
#pragma unroll
    for (int ks = 0; ks < 4; ++ks) {
      const int h2 = ks >> 1, k1 = ks & 1;
      unsigned w0 = wa[h2][2 * k1], w2 = wa[h2][2 * k1 + 1];
      plane_swap(w0, w2);
      unsigned w1 = wb[h2][2 * k1], w3 = wb[h2][2 * k1 + 1];
      plane_swap(w1, w3);
      union { unsigned u[4]; bf16x8 v; } pa;
      pa.u[0] = w0; pa.u[1] = w1; pa.u[2] = w2; pa.u[3] = w3;
#pragma unroll
      for (int nd = 0; nd < 4; ++nd) {
        bf16x8 bv = frag64(Vb, nd * 32 + ln, 2 * ks + hi);
        yacc[nd] = MFMA32(pa.v, bv, yacc[nd]);
      }
    }
    __builtin_amdgcn_s_setprio(0);

    __syncthreads();  // prefetch complete + protects buf swap
    buf ^= 1;
  }

  const int b = bh >> 4, h = bh & 15;
  float inv = 1.f / l;
#pragma unroll
  for (int r = 0; r < 16; ++r) {
    int crow = (r & 3) + 8 * (r >> 2) + 4 * hi;
    float li = __shfl(inv, crow);
    int t = qrow0 + crow;
    size_t rp = ((size_t)b * 2048 + t) * 2048 + h * 128;
#pragma unroll
    for (int nd = 0; nd < 4; ++nd)
      yg[rp + nd * 32 + ln] = f2bf(yacc[nd][r] * li);
  }
}

// ---------------- launch ----------------
extern "C" void kernel_launch(void* const* d_in, const int* in_sizes, int n_in,
                              void* d_out, int out_size, void* d_ws, size_t ws_size,
                              hipStream_t stream) {
  const float* x = (const float*)d_in[0];
  const float* wa = (const float*)d_in[1];
  const float* wp = (const float*)d_in[2];
  float* out = (float*)d_out;

  // workspace layout (bf16 elems)
  u16* xb = (u16*)d_ws;          // 8192x2048
  u16* wab = xb + 16777216;      // 6144x2048
  u16* wpb = wab + 12582912;     // 2048x2048
  u16* qb = wpb + 4194304;       // (B,H,T,D), q pre-scaled (scale*log2e)
  u16* kb = qb + 16777216;       // (B,H,T,D)
  u16* vtb = kb + 16777216;      // (B,H,D,T)
  u16* yb = vtb + 16777216;      // (B,T,C)

  hipFuncSetAttribute((const void*)k_gemm_qkv,
                      hipFuncAttributeMaxDynamicSharedMemorySize, 131072);
  hipFuncSetAttribute((const void*)k_gemm_proj,
                      hipFuncAttributeMaxDynamicSharedMemorySize, 131072);

  k_cast3<<<dim3(2048), dim3(256), 0, stream>>>(
      (const float4*)x, (const float4*)wa, (const float4*)wp,
      (u16x4*)xb, (u16x4*)wab, (u16x4*)wpb);
  k_gemm_qkv<<<dim3(768), dim3(512), 131072, stream>>>(xb, wab, qb, kb, vtb);
  k_attn<<<dim3(512), dim3(512), 0, stream>>>(qb, kb, vtb, yb);
  k_gemm_proj<<<dim3(256), dim3(512), 131072, stream>>>(yb, wpb, out);
}

// Round 16
// 453.513 us; speedup vs baseline: 1.0226x; 1.0226x over previous
//
#include <hip/hip_runtime.h>

#define DEVINL __device__ __forceinline__

typedef unsigned short u16;
typedef __attribute__((ext_vector_type(8))) __bf16 bf16x8;
typedef __attribute__((ext_vector_type(4))) float f32x4;
typedef __attribute__((ext_vector_type(16))) float f32x16;

struct alignas(8) u16x4 { u16 x, y, z, w; };

#define MFMA16(a, b, c) __builtin_amdgcn_mfma_f32_16x16x32_bf16(a, b, c, 0, 0, 0)
#define MFMA32(a, b, c) __builtin_amdgcn_mfma_f32_32x32x16_bf16(a, b, c, 0, 0, 0)

// fp32 -> bf16 round-to-nearest-even
DEVINL u16 f2bf(float f) {
  unsigned u = __builtin_bit_cast(unsigned, f);
  u += 0x7fffu + ((u >> 16) & 1u);
  return (u16)(u >> 16);
}

DEVINL unsigned cvtpk_bf16(float lo, float hi) {
  unsigned r;
  asm("v_cvt_pk_bf16_f32 %0, %1, %2" : "=v"(r) : "v"(lo), "v"(hi));
  return r;
}

// NOTE (R15 lesson): do NOT build reductions from plane_swap with two
// identically-valued operands -- the register allocator may coalesce them
// into ONE register, making the asm a self-swap (wrong result). Safe only
// when the two operands provably hold distinct values (the PV usage below).
DEVINL void plane_swap(unsigned& a, unsigned& b) {
  asm("v_permlane32_swap_b32 %0, %1" : "+v"(a), "+v"(b));
}

DEVINL void gload_lds16(const u16* g, u16* l) {
  __builtin_amdgcn_global_load_lds((const __attribute__((address_space(1))) void*)g,
                                   (__attribute__((address_space(3))) void*)l,
                                   16, 0, 0);
}

// ---- swizzled LDS helpers, 16B chunks: LDS[r][c] = G[r][c ^ (r&7)] ----
DEVINL bf16x8 frag64(const u16* lds, int row, int cg) {
  int c = cg ^ (row & 7);
  return *(const bf16x8*)(lds + row * 64 + c * 8);
}
DEVINL bf16x8 frag128(const u16* lds, int row, int cg) {
  int c = cg ^ (row & 7);
  return *(const bf16x8*)(lds + row * 128 + c * 8);
}

// 512-thread staging (attn, 8 waves): 64x128 K tile, 2 loads/thread
DEVINL void stage_k512(const u16* g, u16* lds, int wave, int lane) {
#pragma unroll
  for (int t = 0; t < 2; ++t) {
    int r = t * 32 + wave * 4 + (lane >> 4);
    int cg = (lane & 15) ^ (r & 7);
    gload_lds16(g + (size_t)r * 128 + cg * 8, lds + (t * 32 + wave * 4) * 128);
  }
}
// 512-thread staging (attn, 8 waves): 128x64 V tile (ldg = global row stride)
DEVINL void stage_v512(const u16* g, int ldg, u16* lds, int wave, int lane) {
#pragma unroll
  for (int t = 0; t < 2; ++t) {
    int r = t * 64 + wave * 8 + (lane >> 3);
    int cg = (lane & 7) ^ (r & 7);
    gload_lds16(g + (size_t)r * ldg + cg * 8, lds + (t * 64 + wave * 8) * 64);
  }
}

// ---- 256x32 sub-tile machinery (64B rows, 4 chunks) for the ring-4 GEMM ----
DEVINL int perm32(int row) { return (row & 3) ^ ((row >> 2) & 3); }

DEVINL void stage32(const u16* g, int ldg, u16* lds, int q, int wave, int lane) {
  int row = q * 128 + wave * 16 + (lane >> 2);
  int cg = (lane & 3) ^ perm32(row);
  gload_lds16(g + (size_t)row * ldg + cg * 8, lds + (q * 128 + wave * 16) * 32);
}

DEVINL bf16x8 frag32(const u16* lds, int row, int lc) {
  int c = lc ^ perm32(row);
  return *(const bf16x8*)(lds + row * 32 + c * 8);
}

// ---------------- fused fp32 -> bf16 cast (all three inputs, one launch) ----------------
// blocks [0,1024): x (4M float4); [1024,1792): w_attn (3M); [1792,2048): w_proj (1M).
__global__ void __launch_bounds__(256) k_cast3(const float4* __restrict__ x,
                                               const float4* __restrict__ wa,
                                               const float4* __restrict__ wp,
                                               u16x4* __restrict__ xb,
                                               u16x4* __restrict__ wab,
                                               u16x4* __restrict__ wpb) {
  const int b = blockIdx.x;
  const float4* src;
  u16x4* dst;
  int n, i, stride;
  if (b < 1024) {
    src = x; dst = xb; n = 4194304;
    i = b * 256 + threadIdx.x; stride = 1024 * 256;
  } else if (b < 1792) {
    src = wa; dst = wab; n = 3145728;
    i = (b - 1024) * 256 + threadIdx.x; stride = 768 * 256;
  } else {
    src = wp; dst = wpb; n = 1048576;
    i = (b - 1792) * 256 + threadIdx.x; stride = 256 * 256;
  }
  for (; i < n; i += stride) {
    float4 f = src[i];
    u16x4 u;
    u.x = f2bf(f.x); u.y = f2bf(f.y); u.z = f2bf(f.z); u.w = f2bf(f.w);
    dst[i] = u;
  }
}

// ---------------- 256x256 ring-4 GEMM, register-pipelined 2-phase steps ----------------
// (R11 structure verbatim -- best measured: 199us / MfmaUtil 46.6% on GEMM1.)
// A row-major (M,K), B row-major (N,K). 8 waves = 2(M) x 4(N); wave (wm,wn)
// owns C rows [wm*128,+128) x cols [wn*64,+64): acc[mf 0..7][nf 0..3].
// Ring: BK=32 sub-tiles in 4 LDS slots/operand (128KB). Per step, 2 phases,
// MFMA operands PRELOADED one phase ahead (reads issue under the previous
// MFMA cluster -> no exposed ds_read latency):
//  phase A: 16 MFMA (aA,bfr = tile s, preloaded) ; read aB(s) ;
//           stage A(s+3) ; vmcnt(6) certify tile s+1 ; barrier
//  phase B: 16 MFMA (aB,bfr) ; read aA,bfr(s+1) [certified above] ;
//           stage B(s+3) ; barrier
// Hazards: stage targets slot (s-1)&3 whose last reads completed before the
// previous trailing barrier; per-wave vmcnt + barrier = collective certify.
// vmcnt units: steady outstanding at wait = 10, drain tile s+1's 4 oldest
// -> vmcnt(6); tail 4 / 0.
DEVINL void gemm_loop256(const u16* Ag, const u16* Bg, int K, u16* smem,
                         f32x4 acc[8][4], int wave, int lane) {
  const int wm = wave >> 2, wn = wave & 3;
  const int lr = lane & 15, lc = lane >> 4;

  // prologue: stage tiles 0,1,2 (12 loads/thread)
#pragma unroll
  for (int t = 0; t < 3; ++t) {
    u16* At = smem + t * 8192;
    u16* Bt = smem + 32768 + t * 8192;
    stage32(Ag + t * 32, K, At, 0, wave, lane);
    stage32(Ag + t * 32, K, At, 1, wave, lane);
    stage32(Bg + t * 32, K, Bt, 0, wave, lane);
    stage32(Bg + t * 32, K, Bt, 1, wave, lane);
  }
  // certify tile 0 (drain its 4 loads; 8 newer stay in flight)
  asm volatile("s_waitcnt vmcnt(8)" ::: "memory");
  asm volatile("s_barrier" ::: "memory");

  // preload step-0 phase-A operands (tile 0)
  bf16x8 bfr[4], aA[4], aB[4];
#pragma unroll
  for (int nf = 0; nf < 4; ++nf)
    bfr[nf] = frag32(smem + 32768, nf * 64 + wn * 16 + lr, lc);
#pragma unroll
  for (int mf = 0; mf < 4; ++mf)
    aA[mf] = frag32(smem, wm * 128 + mf * 16 + lr, lc);

  const int nsteps = K / 32;
  for (int s = 0; s < nsteps; ++s) {
    const int slot = s & 3;
    const u16* Ac = smem + slot * 8192;
    const bool do_stage = (s + 3 < nsteps);
    u16* An = smem + ((s + 3) & 3) * 8192;
    u16* Bn = smem + 32768 + ((s + 3) & 3) * 8192;
    const u16* Agn = Ag + (size_t)(s + 3) * 32;
    const u16* Bgn = Bg + (size_t)(s + 3) * 32;

    // ---- phase A ----
    __builtin_amdgcn_s_setprio(1);
#pragma unroll
    for (int mf = 0; mf < 4; ++mf)
#pragma unroll
      for (int nf = 0; nf < 4; ++nf)
        acc[mf][nf] = MFMA16(aA[mf], bfr[nf], acc[mf][nf]);
    __builtin_amdgcn_s_setprio(0);
#pragma unroll
    for (int mf = 0; mf < 4; ++mf)
      aB[mf] = frag32(Ac, wm * 128 + (mf + 4) * 16 + lr, lc);
    if (do_stage) {
      stage32(Agn, K, An, 0, wave, lane);
      stage32(Agn, K, An, 1, wave, lane);
    }
    if (s + 3 < nsteps) {
      asm volatile("s_waitcnt vmcnt(6)" ::: "memory");
    } else if (s + 2 < nsteps) {
      asm volatile("s_waitcnt vmcnt(4)" ::: "memory");
    } else if (s + 1 < nsteps) {
      asm volatile("s_waitcnt vmcnt(0)" ::: "memory");
    }
    asm volatile("s_barrier" ::: "memory");

    // ---- phase B ----
    __builtin_amdgcn_s_setprio(1);
#pragma unroll
    for (int mf = 0; mf < 4; ++mf)
#pragma unroll
      for (int nf = 0; nf < 4; ++nf)
        acc[mf + 4][nf] = MFMA16(aB[mf], bfr[nf], acc[mf + 4][nf]);
    __builtin_amdgcn_s_setprio(0);
    if (s + 1 < nsteps) {
      const int slot1 = (s + 1) & 3;
      const u16* An1 = smem + slot1 * 8192;
      const u16* Bn1 = smem + 32768 + slot1 * 8192;
#pragma unroll
      for (int nf = 0; nf < 4; ++nf)
        bfr[nf] = frag32(Bn1, nf * 64 + wn * 16 + lr, lc);
#pragma unroll
      for (int mf = 0; mf < 4; ++mf)
        aA[mf] = frag32(An1, wm * 128 + mf * 16 + lr, lc);
    }
    if (do_stage) {
      stage32(Bgn, K, Bn, 0, wave, lane);
      stage32(Bgn, K, Bn, 1, wave, lane);
    }
    asm volatile("s_barrier" ::: "memory");
  }
}

// ---------------- GEMM1: qkv = x @ w_attn^T, fused RoPE + scatter ----------------
// 2D-chunked XCD swizzle: XCD x owns tm in [8(x&3),+8) x tn in [12(x>>2),+12).
// tn 0-7: q, 8-15: k, 16-23: v; 256-col tile = 2 heads.
// q pre-scaled by (1/sqrt(D))*log2(e) so attention softmax runs in exp2 domain.
__global__ void __launch_bounds__(512, 2) k_gemm_qkv(const u16* __restrict__ xb,
                                                     const u16* __restrict__ wab,
                                                     u16* __restrict__ qb,
                                                     u16* __restrict__ kb,
                                                     u16* __restrict__ vtb) {
  extern __shared__ u16 smem[];
  int bid = blockIdx.x;
  const int xcd = bid & 7, local = bid >> 3;       // 96 blocks per XCD
  const int tm = (xcd & 3) * 8 + (local & 7);      // 32 tm
  const int tn = (xcd >> 2) * 12 + (local >> 3);   // 24 tn
  const int wave = threadIdx.x >> 6, lane = threadIdx.x & 63;
  const int wm = wave >> 2, wn = wave & 3;
  const int lr = lane & 15, lc = lane >> 4;

  f32x4 acc[8][4];
#pragma unroll
  for (int i = 0; i < 8; ++i)
#pragma unroll
    for (int n = 0; n < 4; ++n) acc[i][n] = f32x4{0.f, 0.f, 0.f, 0.f};

  gemm_loop256(xb + (size_t)tm * 256 * 2048, wab + (size_t)tn * 256 * 2048, 2048,
               smem, acc, wave, lane);

  const int sel = tn >> 3;
  const int hh = (tn & 7) * 2;
  const int m0 = tm * 256 + wm * 128;
  const int b = (tm * 256) >> 11;

  if (sel < 2) {
    u16* dst = sel ? kb : qb;
    // q: fold 1/sqrt(128) * log2(e) (exp2-domain softmax)
    const float qs = sel ? 1.0f : 0.12751745f;
    const int d = wn * 16 + lr;  // d in [0,64)
    const float invf = __expf(-0.14391156631f * (float)d);
#pragma unroll
    for (int mf = 0; mf < 8; ++mf) {
#pragma unroll
      for (int j = 0; j < 4; ++j) {
        int t = (m0 + mf * 16 + lc * 4 + j) & 2047;
        float ang = (float)t * invf;
        float s, c;
        __sincosf(ang, &s, &c);
#pragma unroll
        for (int hp = 0; hp < 2; ++hp) {
          float lo = acc[mf][2 * hp][j];
          float hi = acc[mf][2 * hp + 1][j];
          size_t rowp = ((size_t)(b * 16 + hh + hp) * 2048 + t) * 128;
          dst[rowp + d] = f2bf((lo * c - hi * s) * qs);
          dst[rowp + d + 64] = f2bf((hi * c + lo * s) * qs);
        }
      }
    }
  } else {
    // v -> (B,H,D,T) transposed; pack 4 consecutive t (j dim) per store
#pragma unroll
    for (int mf = 0; mf < 8; ++mf) {
      int t0 = (m0 + mf * 16 + lc * 4) & 2047;
#pragma unroll
      for (int nf = 0; nf < 4; ++nf) {
        int d = wn * 16 + lr + (nf & 1) * 64;
        int h = hh + (nf >> 1);
        u16x4 pk;
        pk.x = f2bf(acc[mf][nf][0]);
        pk.y = f2bf(acc[mf][nf][1]);
        pk.z = f2bf(acc[mf][nf][2]);
        pk.w = f2bf(acc[mf][nf][3]);
        *(u16x4*)(vtb + ((size_t)(b * 16 + h) * 128 + d) * 2048 + t0) = pk;
      }
    }
  }
}

// ---------------- GEMM2: out = y @ w_proj^T (fp32 out) ----------------
__global__ void __launch_bounds__(512, 2) k_gemm_proj(const u16* __restrict__ yb,
                                                      const u16* __restrict__ wpb,
                                                      float* __restrict__ out) {
  extern __shared__ u16 smem[];
  int bid = blockIdx.x;
  int sw = (bid & 7) * 32 + (bid >> 3);  // 256 = 8 * 32, bijective
  const int tm = sw >> 3, tn = sw & 7;   // XCD x -> tm in [4x, 4x+3]
  const int wave = threadIdx.x >> 6, lane = threadIdx.x & 63;
  const int wm = wave >> 2, wn = wave & 3;
  const int lr = lane & 15, lc = lane >> 4;

  f32x4 acc[8][4];
#pragma unroll
  for (int i = 0; i < 8; ++i)
#pragma unroll
    for (int n = 0; n < 4; ++n) acc[i][n] = f32x4{0.f, 0.f, 0.f, 0.f};

  gemm_loop256(yb + (size_t)tm * 256 * 2048, wpb + (size_t)tn * 256 * 2048, 2048,
               smem, acc, wave, lane);

  const int m0 = tm * 256 + wm * 128;
#pragma unroll
  for (int mf = 0; mf < 8; ++mf) {
#pragma unroll
    for (int j = 0; j < 4; ++j) {
      int gr = m0 + mf * 16 + lc * 4 + j;
      float* op = out + (size_t)gr * 2048 + tn * 256 + wn * 16 + lr;
#pragma unroll
      for (int nf = 0; nf < 4; ++nf) op[nf * 64] = acc[mf][nf][j];
    }
  }
}

// ---------------- flash attention, 8-wave blocks (R9 structure, shfl reduces) ----------------
__global__ void __launch_bounds__(512) k_attn(const u16* __restrict__ qg,
                                              const u16* __restrict__ kg,
                                              const u16* __restrict__ vtg,
                                              u16* __restrict__ yg) {
  __shared__ u16 Ks[2][64 * 128];  // [buf][kv][d], 32 KB
  __shared__ u16 Vs[2][128 * 64];  // [buf][d][kv], 32 KB
  int bid = blockIdx.x;
  int sw = (bid & 7) * 64 + (bid >> 3);  // 512 = 8 * 64, bijective
  const int qt = sw & 7, bh = sw >> 3;   // XCD x -> 8 heads, all their q-tiles
  const int wave = threadIdx.x >> 6, lane = threadIdx.x & 63;
  const int hi = lane >> 5, ln = lane & 31;

  const u16* qbh = qg + (size_t)bh * (2048 * 128);
  const u16* kbh = kg + (size_t)bh * (2048 * 128);
  const u16* vbh = vtg + (size_t)bh * (128 * 2048);
  const int qrow0 = qt * 256 + wave * 32;

  // hoist Q (B-operand): lane holds Q[q=ln][d = kc*16 + hi*8 .. +7]
  bf16x8 qf[8];
#pragma unroll
  for (int kc = 0; kc < 8; ++kc)
    qf[kc] = *(const bf16x8*)(qbh + (size_t)(qrow0 + ln) * 128 + kc * 16 + hi * 8);

  f32x16 yacc[4];
#pragma unroll
  for (int nd = 0; nd < 4; ++nd)
#pragma unroll
    for (int r = 0; r < 16; ++r) yacc[nd][r] = 0.f;
  float m = -1e30f, l = 0.f;

  stage_k512(kbh, Ks[0], wave, lane);
  stage_v512(vbh, 2048, Vs[0], wave, lane);
  __syncthreads();

  int buf = 0;
  for (int kv0 = 0; kv0 < 2048; kv0 += 64) {
    if (kv0 + 64 < 2048) {
      stage_k512(kbh + (size_t)(kv0 + 64) * 128, Ks[buf ^ 1], wave, lane);
      stage_v512(vbh + kv0 + 64, 2048, Vs[buf ^ 1], wave, lane);
    }
    const u16* Kb = Ks[buf];
    const u16* Vb = Vs[buf];

    // QK^T: st[h2] = S^T[kv = h2*32 .. +32][q]
    f32x16 st[2];
#pragma unroll
    for (int h2 = 0; h2 < 2; ++h2)
#pragma unroll
      for (int r = 0; r < 16; ++r) st[h2][r] = 0.f;
    __builtin_amdgcn_s_setprio(1);
#pragma unroll
    for (int kc = 0; kc < 8; ++kc) {
      bf16x8 a0 = frag128(Kb, ln, kc * 2 + hi);
      bf16x8 a1 = frag128(Kb, 32 + ln, kc * 2 + hi);
      st[0] = MFMA32(a0, qf[kc], st[0]);
      st[1] = MFMA32(a1, qf[kc], st[1]);
    }
    __builtin_amdgcn_s_setprio(0);

    float t8[8];
#pragma unroll
    for (int i = 0; i < 8; ++i)
      t8[i] = fmaxf(fmaxf(st[0][i], st[0][i + 8]), fmaxf(st[1][i], st[1][i + 8]));
    float pmax = fmaxf(fmaxf(fmaxf(t8[0], t8[4]), fmaxf(t8[1], t8[5])),
                       fmaxf(fmaxf(t8[2], t8[6]), fmaxf(t8[3], t8[7])));
    pmax = fmaxf(pmax, __shfl_xor(pmax, 32));

    // defer-max: THR = 8 * log2(e) in exp2 domain
    if (__any(pmax - m > 11.5415603f)) {
      float mn = fmaxf(m, pmax);
      float al = __builtin_amdgcn_exp2f(m - mn);
      m = mn;
      l *= al;
#pragma unroll
      for (int nd = 0; nd < 4; ++nd)
#pragma unroll
        for (int r = 0; r < 16; ++r) yacc[nd][r] *= al;
    }

    float sa0 = 0.f, sa1 = 0.f, sa2 = 0.f, sa3 = 0.f;
#pragma unroll
    for (int h2 = 0; h2 < 2; ++h2) {
#pragma unroll
      for (int r = 0; r < 16; ++r) {
        float e = __builtin_amdgcn_exp2f(st[h2][r] - m);
        st[h2][r] = e;
        if ((r & 3) == 0) sa0 += e;
        else if ((r & 3) == 1) sa1 += e;
        else if ((r & 3) == 2) sa2 += e;
        else sa3 += e;
      }
    }
    float ssum = (sa0 + sa1) + (sa2 + sa3);
    ssum += __shfl_xor(ssum, 32);
    l += ssum;

    unsigned wa[2][4], wb[2][4];
#pragma unroll
    for (int h2 = 0; h2 < 2; ++h2)
#pragma unroll
      for (int q8 = 0; q8 < 4; ++q8) {
        wa[h2][q8] = cvtpk_bf16(st[h2][q8 * 4 + 0], st[h2][q8 * 4 + 1]);
        wb[h2][q8] = cvtpk_bf16(st[h2][q8 * 4 + 2], st[h2][q8 * 4 + 3]);
      }

    // PV: 4 kv16-blocks; pa assembled by permlane32_swap (operands distinct -- safe)
    __builtin_amdgcn_s_setprio(1);
#pragma unroll
    for (int ks = 0; ks < 4; ++ks) {
      const int h2 = ks >> 1, k1 = ks & 1;
      unsigned w0 = wa[h2][2 * k1], w2 = wa[h2][2 * k1 + 1];
      plane_swap(w0, w2);
      unsigned w1 = wb[h2][2 * k1], w3 = wb[h2][2 * k1 + 1];
      plane_swap(w1, w3);
      union { unsigned u[4]; bf16x8 v; } pa;
      pa.u[0] = w0; pa.u[1] = w1; pa.u[2] = w2; pa.u[3] = w3;
#pragma unroll
      for (int nd = 0; nd < 4; ++nd) {
        bf16x8 bv = frag64(Vb, nd * 32 + ln, 2 * ks + hi);
        yacc[nd] = MFMA32(pa.v, bv, yacc[nd]);
      }
    }
    __builtin_amdgcn_s_setprio(0);

    __syncthreads();  // prefetch complete + protects buf swap
    buf ^= 1;
  }

  const int b = bh >> 4, h = bh & 15;
  float inv = 1.f / l;
#pragma unroll
  for (int r = 0; r < 16; ++r) {
    int crow = (r & 3) + 8 * (r >> 2) + 4 * hi;
    float li = __shfl(inv, crow);
    int t = qrow0 + crow;
    size_t rp = ((size_t)b * 2048 + t) * 2048 + h * 128;
#pragma unroll
    for (int nd = 0; nd < 4; ++nd)
      yg[rp + nd * 32 + ln] = f2bf(yacc[nd][r] * li);
  }
}

// ---------------- launch ----------------
extern "C" void kernel_launch(void* const* d_in, const int* in_sizes, int n_in,
                              void* d_out, int out_size, void* d_ws, size_t ws_size,
                              hipStream_t stream) {
  const float* x = (const float*)d_in[0];
  const float* wa = (const float*)d_in[1];
  const float* wp = (const float*)d_in[2];
  float* out = (float*)d_out;

  // workspace layout (bf16 elems)
  u16* xb = (u16*)d_ws;          // 8192x2048
  u16* wab = xb + 16777216;      // 6144x2048
  u16* wpb = wab + 12582912;     // 2048x2048
  u16* qb = wpb + 4194304;       // (B,H,T,D), q pre-scaled (scale*log2e)
  u16* kb = qb + 16777216;       // (B,H,T,D)
  u16* vtb = kb + 16777216;      // (B,H,D,T)
  u16* yb = vtb + 16777216;      // (B,T,C)

  hipFuncSetAttribute((const void*)k_gemm_qkv,
                      hipFuncAttributeMaxDynamicSharedMemorySize, 131072);
  hipFuncSetAttribute((const void*)k_gemm_proj,
                      hipFuncAttributeMaxDynamicSharedMemorySize, 131072);

  k_cast3<<<dim3(2048), dim3(256), 0, stream>>>(
      (const float4*)x, (const float4*)wa, (const float4*)wp,
      (u16x4*)xb, (u16x4*)wab, (u16x4*)wpb);
  k_gemm_qkv<<<dim3(768), dim3(512), 131072, stream>>>(xb, wab, qb, kb, vtb);
  k_attn<<<dim3(512), dim3(512), 0, stream>>>(qb, kb, vtb, yb);
  k_gemm_proj<<<dim3(256), dim3(512), 131072, stream>>>(yb, wpb, out);
}